// Round 1
// baseline (264.800 us; speedup 1.0000x reference)
//
#include <hip/hip_runtime.h>
#include <hip/hip_bf16.h>

// CausalSelfAttention: B=4 T=2048 C=1024 H=16 D=64
// ws layout (bytes):
//   xb   @ 0         : x as bf16           [8192][1024]   16 MB
//   wat  @ 16777216  : w_attn^T bf16       [3072][1024]    6 MB
//   wpt  @ 23068672  : w_proj^T bf16       [1024][1024]    2 MB
//   Qb   @ 25165824  : Q bf16 (pre-scaled by 0.125*log2e) [B,H,T,D] 16 MB
//   Kb   @ 41943040  : K bf16  [B,H,T,D]                  16 MB
//   Vtb  @ 58720256  : V^T bf16 [B,H,D,T]  (written directly by gemm_qkv)
//   Ob   @ 75497472  : attn out bf16 [8192][1024]         16 MB
//
// R12: gemm_qkv ported to the 256x256 8-phase counted-vmcnt schedule
// (T3+T4+T5). 512 thr / 8 waves (2Mx4N), BK=64, 128KB LDS double-buffer,
// split-ksub [row][32] LDS layout (64B rows -> bank-uniform b128 frag reads,
// no swizzle, linear global_load_lds dests). vmcnt(4) per K-tile boundary,
// never 0 in steady state. gemm_proj/prep/flash_attn unchanged from R11.

typedef float f32x4 __attribute__((ext_vector_type(4)));
typedef float f32x16 __attribute__((ext_vector_type(16)));
typedef short short8 __attribute__((ext_vector_type(8)));
typedef short short4v __attribute__((ext_vector_type(4)));

__device__ __forceinline__ short f2bf(float f) {
  union { __hip_bfloat16 h; short s; } u;
  u.h = __float2bfloat16(f);
  return u.s;
}

__device__ __forceinline__ void gl_lds16(const void* g, void* l) {
  __builtin_amdgcn_global_load_lds(
      (const __attribute__((address_space(1))) void*)g,
      (__attribute__((address_space(3))) void*)l, 16, 0, 0);
}

// ---------------- fused prep: x cvt + w_attn^T + w_proj^T -------------------
__global__ void prep(const float* __restrict__ x, const float* __restrict__ wa,
                     const float* __restrict__ wp, short* __restrict__ xb,
                     short* __restrict__ wat, short* __restrict__ wpt) {
  const int bid = blockIdx.x, tid = threadIdx.x;
  if (bid < 8192) {
    int i = (bid * 256 + tid) * 4;
    float4 v = *(const float4*)(x + i);
    short4v o;
    o[0] = f2bf(v.x); o[1] = f2bf(v.y); o[2] = f2bf(v.z); o[3] = f2bf(v.w);
    *(short4v*)(xb + i) = o;
    return;
  }
  __shared__ float tile[32][33];
  const float* in;
  short* out;
  int N, bx, by;
  if (bid < 11264) {
    int t = bid - 8192;
    in = wa; out = wat; N = 3072; bx = t % 96; by = t / 96;
  } else {
    int t = bid - 11264;
    in = wp; out = wpt; N = 1024; bx = t & 31; by = t >> 5;
  }
  int tx = tid & 31, ty = tid >> 5;  // 32 x 8
  int x0 = bx * 32, y0 = by * 32;
#pragma unroll
  for (int i = 0; i < 32; i += 8)
    tile[ty + i][tx] = in[(size_t)(y0 + ty + i) * N + x0 + tx];
  __syncthreads();
#pragma unroll
  for (int i = 0; i < 32; i += 8)
    out[(size_t)(x0 + ty + i) * 1024 + y0 + tx] = f2bf(tile[tx][ty + i]);
}

// ------------- legacy GEMM core (128x128, BK=32, 4 waves) — gemm_proj ------
#define GEMM_BODY(A_, Bt_)                                                        \
  __shared__ __align__(16) short As[128 * 32];                                    \
  __shared__ __align__(16) short Bs[128 * 32];                                    \
  const int tid = threadIdx.x;                                                    \
  const int wv = tid >> 6;                                                        \
  const int wr = wv >> 1, wc = wv & 1;                                            \
  const int col = tid & 31, khalf = (tid >> 5) & 1;                               \
  const int m0 = blockIdx.y * 128, n0 = blockIdx.x * 128;                         \
  f32x16 acc[2][2];                                                               \
  _Pragma("unroll") for (int i = 0; i < 2; ++i)                                   \
      _Pragma("unroll") for (int j = 0; j < 2; ++j)                               \
          acc[i][j] = (f32x16)(0.f);                                              \
  for (int k0 = 0; k0 < 1024; k0 += 32) {                                         \
    _Pragma("unroll") for (int i = 0; i < 2; ++i) {                               \
      int cc = tid + i * 256;                                                     \
      int row = cc >> 2, part = ((cc & 3) - ((cc >> 3) & 3)) & 3;                 \
      gl_lds16(A_ + (size_t)(m0 + row) * 1024 + k0 + part * 8,                    \
               (char*)As + cc * 16);                                              \
      gl_lds16(Bt_ + (size_t)(n0 + row) * 1024 + k0 + part * 8,                   \
               (char*)Bs + cc * 16);                                              \
    }                                                                             \
    __syncthreads();                                                              \
    short8 af[2][2], bf[2][2];                                                    \
    _Pragma("unroll") for (int i = 0; i < 2; ++i)                                 \
        _Pragma("unroll") for (int s = 0; s < 2; ++s) {                           \
          int pa = s * 2 + khalf;                                                 \
          int ra = wr * 64 + i * 32 + col;                                        \
          int rb = wc * 64 + i * 32 + col;                                        \
          af[i][s] = *(const short8*)&As[(ra * 4 + ((pa + (ra >> 1)) & 3)) * 8];  \
          bf[i][s] = *(const short8*)&Bs[(rb * 4 + ((pa + (rb >> 1)) & 3)) * 8];  \
        }                                                                         \
    _Pragma("unroll") for (int s = 0; s < 2; ++s)                                 \
        _Pragma("unroll") for (int i = 0; i < 2; ++i)                             \
            _Pragma("unroll") for (int j = 0; j < 2; ++j)                         \
                acc[i][j] = __builtin_amdgcn_mfma_f32_32x32x16_bf16(              \
                    af[i][s], bf[j][s], acc[i][j], 0, 0, 0);                      \
    __syncthreads();                                                              \
  }

__global__ __launch_bounds__(256, 2) void gemm_proj(
    const short* __restrict__ A, const short* __restrict__ Bt,
    const float* __restrict__ bias, float* __restrict__ out) {
  GEMM_BODY(A, Bt)
  const int rhalf = khalf * 4;
#pragma unroll
  for (int i = 0; i < 2; ++i) {
#pragma unroll
    for (int j = 0; j < 2; ++j) {
      int n = n0 + wc * 64 + j * 32 + col;
      float bv = bias[n];
      int mb = m0 + wr * 64 + i * 32 + rhalf;
#pragma unroll
      for (int a = 0; a < 16; ++a) {
        int m = mb + (a & 3) + 8 * (a >> 2);
        out[(size_t)m * 1024 + n] = acc[i][j][a] + bv;
      }
    }
  }
}

// ------------- QKV GEMM: 256x256 tile, BK=64, 8-phase counted-vmcnt --------
// LDS per buffer: A[2 ksub][256 rows][32 cols] bf16 (16KB/ksub), B same.
// 64B row stride -> 16x16x32 frag ds_read_b128 is bank-uniform (8 lanes per
// 4-bank group) with NO swizzle; global_load_lds dests stay linear.
// Phase p of tile kt: p0=(ks0,mh0) stage A(kt+1)ks1; p1=(ks0,mh1) stage
// B(kt+1)ks1; p2=(ks1,mh0) stage A(kt+2)ks0; p3=(ks1,mh1) stage B(kt+2)ks0.
// Boundary wait: vmcnt(4) (leaves the 2 newest half-tiles in flight);
// vmcnt(0) only entering the last tile (its ks1 halves are the newest).

#define LGKM0() asm volatile("s_waitcnt lgkmcnt(0)" ::: "memory")
#define BARRIER() asm volatile("s_barrier" ::: "memory")

#define STG(KT, S, SRC, LB)                                                \
  if ((KT) < 16) {                                                         \
    char* db_ = (char*)(LB) + (((KT) & 1) ? 32768 : 0) + ((S) * 16384);    \
    const short* sb_ = (SRC) + (KT) * 64 + (S) * 32;                       \
    gl_lds16(sb_ + g_off0, db_ + d_off0);                                  \
    gl_lds16(sb_ + g_off1, db_ + d_off1);                                  \
  }

#define LDA(S, MH)                                                         \
  _Pragma("unroll") for (int mt_ = 0; mt_ < 4; ++mt_)                      \
      af[mt_] = *(const short8*)(Ab + (S)*16384 + (MH)*4096 + arow_off +   \
                                 mt_ * 1024);

#define LDB(S)                                                             \
  _Pragma("unroll") for (int nt_ = 0; nt_ < 4; ++nt_)                      \
      bf[nt_] = *(const short8*)(Bb + (S)*16384 + brow_off + nt_ * 1024);

#define MFMA16(MH)                                                         \
  LGKM0();                                                                 \
  __builtin_amdgcn_s_setprio(1);                                           \
  _Pragma("unroll") for (int mt_ = 0; mt_ < 4; ++mt_)                      \
      _Pragma("unroll") for (int nt_ = 0; nt_ < 4; ++nt_)                  \
          acc[(MH)*4 + mt_][nt_] =                                         \
              __builtin_amdgcn_mfma_f32_16x16x32_bf16(                     \
                  af[mt_], bf[nt_], acc[(MH)*4 + mt_][nt_], 0, 0, 0);      \
  __builtin_amdgcn_s_setprio(0);

__global__ __launch_bounds__(512, 2) void gemm_qkv(
    const short* __restrict__ A, const short* __restrict__ Bt,
    const float* __restrict__ bias, short* __restrict__ Qb,
    short* __restrict__ Kb, short* __restrict__ Vtb) {
  __shared__ __align__(16) short Asm[2][16384];  // 64KB
  __shared__ __align__(16) short Bsm[2][16384];  // 64KB
  const int tid = threadIdx.x;
  const int wv = tid >> 6;               // 0..7
  const int wr = wv >> 2, wc = wv & 3;   // 2M x 4N waves
  const int ln16 = tid & 15, q4 = (tid >> 4) & 3;
  const int m0 = blockIdx.y * 256, n0 = blockIdx.x * 256;

  // staging offsets: chunk c = tid (+512); row = c>>2, colpart = c&3
  const int d_off0 = tid * 16, d_off1 = d_off0 + 8192;
  const size_t g_off0 = (size_t)(tid >> 2) * 1024 + (size_t)(tid & 3) * 8;
  const size_t g_off1 = g_off0 + (size_t)128 * 1024;

  // fragment read offsets (bytes within a ksub region)
  const int arow_off = (wr * 128 + ln16) * 64 + q4 * 16;
  const int brow_off = (wc * 64 + ln16) * 64 + q4 * 16;

  const short* srcA = A + (size_t)m0 * 1024;
  const short* srcB = Bt + (size_t)n0 * 1024;

  f32x4 acc[8][4];
#pragma unroll
  for (int i = 0; i < 8; ++i)
#pragma unroll
    for (int j = 0; j < 4; ++j) acc[i][j] = (f32x4){0.f, 0.f, 0.f, 0.f};

  // prologue: tile0 complete + tile1 ksub0 (tile1 ksub1 staged in tile0 p0/p1)
  STG(0, 0, srcA, Asm)
  STG(0, 0, srcB, Bsm)
  STG(0, 1, srcA, Asm)
  STG(0, 1, srcB, Bsm)
  STG(1, 0, srcA, Asm)
  STG(1, 0, srcB, Bsm)
  asm volatile("s_waitcnt vmcnt(4)" ::: "memory");
  BARRIER();

  for (int kt = 0; kt < 16; ++kt) {
    const char* Ab = (const char*)Asm + ((kt & 1) ? 32768 : 0);
    const char* Bb = (const char*)Bsm + ((kt & 1) ? 32768 : 0);
    short8 af[4], bf[4];
    // phase 0: ksub0, mhalf0
    LDB(0)
    LDA(0, 0)
    STG(kt + 1, 1, srcA, Asm)
    BARRIER();
    MFMA16(0)
    BARRIER();
    // phase 1: ksub0, mhalf1 (reuse bf)
    LDA(0, 1)
    STG(kt + 1, 1, srcB, Bsm)
    BARRIER();
    MFMA16(1)
    BARRIER();
    // phase 2: ksub1, mhalf0
    LDB(1)
    LDA(1, 0)
    STG(kt + 2, 0, srcA, Asm)
    BARRIER();
    MFMA16(0)
    BARRIER();
    // phase 3: ksub1, mhalf1
    LDA(1, 1)
    STG(kt + 2, 0, srcB, Bsm)
    BARRIER();
    MFMA16(1)
    // K-tile boundary: counted wait, never 0 in steady state
    if (kt == 14) {
      asm volatile("s_waitcnt vmcnt(0)" ::: "memory");
    } else {
      asm volatile("s_waitcnt vmcnt(4)" ::: "memory");
    }
    BARRIER();
  }

  // epilogue: C/D map per 16x16 tile: n_local = lane&15, m_local = q4*4 + r
  // acc[i][nt]: rowbase = (i>>2)*64 + (i&3)*16
#pragma unroll
  for (int nt = 0; nt < 4; ++nt) {
    int n = n0 + wc * 64 + nt * 16 + ln16;
    float bv = bias[n];
    int n2 = n & 1023;
    int hcol = n2 >> 6, d = n2 & 63;
#pragma unroll
    for (int i = 0; i < 8; ++i) {
      int mb = m0 + wr * 128 + (i >> 2) * 64 + (i & 3) * 16 + q4 * 4;
      int bh = ((mb >> 11) << 4) + hcol;
      if (n < 2048) {  // Q or K: [bh][t][d], scalar b16 stores
        const bool isq = n < 1024;
#pragma unroll
        for (int r = 0; r < 4; ++r) {
          int t = (mb + r) & 2047;
          float o = acc[i][nt][r] + bv;
          size_t idx = ((size_t)bh * 2048 + t) * 64 + d;
          if (isq)
            Qb[idx] = f2bf(o * 0.18033688f);
          else
            Kb[idx] = f2bf(o);
        }
      } else {  // V^T: [bh][d][t], b64 store over the 4 consecutive t
        int t = mb & 2047;
        short4v o;
#pragma unroll
        for (int r = 0; r < 4; ++r) o[r] = f2bf(acc[i][nt][r] + bv);
        *(short4v*)&Vtb[((size_t)bh * 64 + d) * 2048 + t] = o;
      }
    }
  }
}

// ---------------- flash attention (R10 version — kept) ----------------------
__global__ __launch_bounds__(256, 2) void flash_attn(
    const short* __restrict__ Qg_, const short* __restrict__ Kg_,
    const short* __restrict__ Vg_, short* __restrict__ Ob) {
  constexpr int STR = 72;  // padded rows: rotates bank window 4/row
  __shared__ __align__(16) short Kl[2][64 * STR];
  __shared__ __align__(16) short Vl[2][64 * STR];
  const int tid = threadIdx.x;
  const int wv = tid >> 6, ln = tid & 15, quad = (tid & 63) >> 4;
  const int bh = blockIdx.x & 63;
  const int pair = blockIdx.x >> 6;
  const short* Qg = Qg_ + (size_t)bh * 2048 * 64;
  const short* Kg = Kg_ + (size_t)bh * 2048 * 64;
  const short* Vg = Vg_ + (size_t)bh * 64 * 2048;
  const int srow = tid >> 3, spart = tid & 7;
  const int bb = bh >> 4, hh = bh & 15;

  short8 kreg[2], vreg[2];

#define LOADKV(KT)                                                              \
  {                                                                             \
    const short* Kt = Kg + (size_t)(KT) * 64 * 64;                              \
    _Pragma("unroll") for (int i = 0; i < 2; ++i) {                             \
      kreg[i] = *(const short8*)(Kt + (size_t)(srow + i * 32) * 64 + spart * 8);\
      vreg[i] = *(const short8*)(Vg + (size_t)(srow + i * 32) * 2048 +          \
                                 (KT) * 64 + spart * 8);                        \
    }                                                                           \
  }
#define WRITEKV(BUF)                                                            \
  _Pragma("unroll") for (int i = 0; i < 2; ++i) {                               \
    *(short8*)&Kl[BUF][(srow + i * 32) * STR + spart * 8] = kreg[i];            \
    *(short8*)&Vl[BUF][(srow + i * 32) * STR + spart * 8] = vreg[i];            \
  }

#pragma unroll
  for (int it = 0; it < 2; ++it) {
    const int qt = it ? pair : (15 - pair);  // long item first
    const int q0 = qt * 128;
    const int qbase = q0 + wv * 32;
    const int nkt = (q0 >> 6) + 2;

    short8 qf[2][2];
#pragma unroll
    for (int h = 0; h < 2; ++h)
#pragma unroll
      for (int ch = 0; ch < 2; ++ch)
        qf[h][ch] = *(const short8*)(Qg + (size_t)(qbase + h * 16 + ln) * 64 +
                                     ch * 32 + quad * 8);

    f32x4 Oacc[2][4];
#pragma unroll
    for (int h = 0; h < 2; ++h)
#pragma unroll
      for (int mt = 0; mt < 4; ++mt) Oacc[h][mt] = (f32x4){0.f, 0.f, 0.f, 0.f};
    float lpart[2] = {0.f, 0.f};

    LOADKV(0)
    __syncthreads();  // previous item's readers of buf0 done
    WRITEKV(0)
    LOADKV(1)

    for (int kt = 0; kt < nkt; ++kt) {
      __syncthreads();  // buf[kt&1] staged; prev readers of buf[(kt+1)&1] done
      const short* Kcur = Kl[kt & 1];
      const short* Vcur = Vl[kt & 1];
      if (kt + 1 < nkt) {
        WRITEKV((kt + 1) & 1)  // overlaps this iter's compute reads
        if (kt + 2 < nkt) LOADKV(kt + 2)
      }

      if (kt * 64 <= qbase + 31) {  // wave-uniform skip of fully-masked tiles
        f32x4 St[2][4];
#pragma unroll
        for (int h = 0; h < 2; ++h)
#pragma unroll
          for (int kb = 0; kb < 4; ++kb) St[h][kb] = (f32x4){0.f, 0.f, 0.f, 0.f};
#pragma unroll
        for (int kb = 0; kb < 4; ++kb) {
          short8 ka0 = *(const short8*)&Kcur[(kb * 16 + ln) * STR + quad * 8];
          short8 ka1 = *(const short8*)&Kcur[(kb * 16 + ln) * STR + 32 + quad * 8];
#pragma unroll
          for (int h = 0; h < 2; ++h) {
            St[h][kb] = __builtin_amdgcn_mfma_f32_16x16x32_bf16(
                ka0, qf[h][0], St[h][kb], 0, 0, 0);
            St[h][kb] = __builtin_amdgcn_mfma_f32_16x16x32_bf16(
                ka1, qf[h][1], St[h][kb], 0, 0, 0);
          }
        }

        // p = exp2(s); l partials; pack. Mask only on the diagonal tile
        // (wave-uniform branch; ~6% of iters).
        short4v pf[2][4];
#pragma unroll
        for (int h = 0; h < 2; ++h) {
          float lp0 = 0.f, lp1 = 0.f;
          if (kt * 64 + 63 <= qbase + h * 16) {  // fully unmasked
#pragma unroll
            for (int kb = 0; kb < 4; ++kb) {
              float p[4];
#pragma unroll
              for (int r = 0; r < 4; ++r)
                p[r] = __builtin_amdgcn_exp2f(St[h][kb][r]);
              lp0 += p[0] + p[2];
              lp1 += p[1] + p[3];
              union { __hip_bfloat162 b2; unsigned u; } w0, w1;
              w0.b2 = __float22bfloat162_rn(make_float2(p[0], p[1]));
              w1.b2 = __float22bfloat162_rn(make_float2(p[2], p[3]));
              union { short4v s4; unsigned u2[2]; } m;
              m.u2[0] = w0.u; m.u2[1] = w1.u;
              pf[h][kb] = m.s4;
            }
          } else {  // diagonal tile: per-element causal mask
            const int qg = qbase + h * 16 + ln;
#pragma unroll
            for (int kb = 0; kb < 4; ++kb) {
              float p[4];
#pragma unroll
              for (int r = 0; r < 4; ++r) {
                int key = kt * 64 + kb * 16 + quad * 4 + r;
                float s = (key <= qg) ? St[h][kb][r] : -1e30f;
                p[r] = __builtin_amdgcn_exp2f(s);
              }
              lp0 += p[0] + p[2];
              lp1 += p[1] + p[3];
              union { __hip_bfloat162 b2; unsigned u; } w0, w1;
              w0.b2 = __float22bfloat162_rn(make_float2(p[0], p[1]));
              w1.b2 = __float22bfloat162_rn(make_float2(p[2], p[3]));
              union { short4v s4; unsigned u2[2]; } m;
              m.u2[0] = w0.u; m.u2[1] = w1.u;
              pf[h][kb] = m.s4;
            }
          }
          lpart[h] += lp0 + lp1;
        }

#pragma unroll
        for (int kb = 0; kb < 4; ++kb)
#pragma unroll
          for (int mt = 0; mt < 4; ++mt) {
            short4v va =
                *(const short4v*)&Vcur[(mt * 16 + ln) * STR + kb * 16 + quad * 4];
#pragma unroll
            for (int h = 0; h < 2; ++h)
              Oacc[h][mt] = __builtin_amdgcn_mfma_f32_16x16x16bf16_1k(
                  va, pf[h][kb], Oacc[h][mt], 0, 0, 0);
          }
      }
    }

#pragma unroll
    for (int h = 0; h < 2; ++h) {
      float l = lpart[h];
      l += __shfl_xor(l, 16);
      l += __shfl_xor(l, 32);
      float rl = 1.0f / l;
      int t = qbase + h * 16 + ln;
#pragma unroll
      for (int mt = 0; mt < 4; ++mt) {
        short4v o;
#pragma unroll
        for (int r = 0; r < 4; ++r) o[r] = f2bf(Oacc[h][mt][r] * rl);
        *(short4v*)(Ob + ((size_t)(bb * 2048 + t)) * 1024 + hh * 64 + mt * 16 +
                    quad * 4) = o;
      }
    }
  }
#undef LOADKV
#undef WRITEKV
}

// ---------------- launcher ----------------

extern "C" void kernel_launch(void* const* d_in, const int* in_sizes, int n_in,
                              void* d_out, int out_size, void* d_ws, size_t ws_size,
                              hipStream_t stream) {
  const float* x      = (const float*)d_in[0];
  const float* w_attn = (const float*)d_in[1];
  const float* b_attn = (const float*)d_in[2];
  const float* w_proj = (const float*)d_in[3];
  const float* b_proj = (const float*)d_in[4];
  float* out = (float*)d_out;
  char* ws = (char*)d_ws;

  short* xb  = (short*)(ws);
  short* wat = (short*)(ws + 16777216);
  short* wpt = (short*)(ws + 23068672);
  short* Qb  = (short*)(ws + 25165824);
  short* Kb  = (short*)(ws + 41943040);
  short* Vtb = (short*)(ws + 58720256);
  short* Ob  = (short*)(ws + 75497472);

  prep<<<12288, 256, 0, stream>>>(x, w_attn, w_proj, xb, wat, wpt);
  gemm_qkv<<<dim3(12, 32), 512, 0, stream>>>(xb, wat, b_attn, Qb, Kb, Vtb);
  flash_attn<<<512, 256, 0, stream>>>(Qb, Kb, Vtb, Ob);
  gemm_proj<<<dim3(8, 64), 256, 0, stream>>>(Ob, wpt, b_proj, out);
}

// Round 2
// 261.259 us; speedup vs baseline: 1.0136x; 1.0136x over previous
//
#include <hip/hip_runtime.h>
#include <hip/hip_bf16.h>

// CausalSelfAttention: B=4 T=2048 C=1024 H=16 D=64
// ws layout (bytes):
//   xb   @ 0         : x as bf16           [8192][1024]   16 MB
//   wat  @ 16777216  : w_attn^T bf16       [3072][1024]    6 MB
//   wpt  @ 23068672  : w_proj^T bf16       [1024][1024]    2 MB
//   Qb   @ 25165824  : Q bf16 (pre-scaled by 0.125*log2e) [B,H,T,D] 16 MB
//   Kb   @ 41943040  : K bf16  [B,H,T,D]                  16 MB
//   Vtb  @ 58720256  : V^T bf16 [B,H,D,T]  (written directly by gemm_qkv)
//   Ob   @ 75497472  : attn out bf16 [8192][1024]         16 MB
//
// R13: R12's 256x256 8-phase schedule + ROTATION SWIZZLE on the LDS chunks
// (R12 post-mortem: unswizzled [256][32] rows put each 16-lane quarter on
// only 2 of 8 bank groups -> 4x LDS-read penalty, 4.7M conflicts, MfmaUtil
// 17.9). Chunk cc of a ksub region holds k-part pa=((cc&3)-((cc>>3)&3))&3
// (pre-swizzled global src, linear LDS dest); frag read slot=(q4+(row>>1))&3
// == (q4+(ln16>>1))&3 (wave/mt bases are multiples of 16 -> per-thread
// constant). Same swizzle family as the R9 128^2 kernel.

typedef float f32x4 __attribute__((ext_vector_type(4)));
typedef float f32x16 __attribute__((ext_vector_type(16)));
typedef short short8 __attribute__((ext_vector_type(8)));
typedef short short4v __attribute__((ext_vector_type(4)));

__device__ __forceinline__ short f2bf(float f) {
  union { __hip_bfloat16 h; short s; } u;
  u.h = __float2bfloat16(f);
  return u.s;
}

__device__ __forceinline__ void gl_lds16(const void* g, void* l) {
  __builtin_amdgcn_global_load_lds(
      (const __attribute__((address_space(1))) void*)g,
      (__attribute__((address_space(3))) void*)l, 16, 0, 0);
}

// ---------------- fused prep: x cvt + w_attn^T + w_proj^T -------------------
__global__ void prep(const float* __restrict__ x, const float* __restrict__ wa,
                     const float* __restrict__ wp, short* __restrict__ xb,
                     short* __restrict__ wat, short* __restrict__ wpt) {
  const int bid = blockIdx.x, tid = threadIdx.x;
  if (bid < 8192) {
    int i = (bid * 256 + tid) * 4;
    float4 v = *(const float4*)(x + i);
    short4v o;
    o[0] = f2bf(v.x); o[1] = f2bf(v.y); o[2] = f2bf(v.z); o[3] = f2bf(v.w);
    *(short4v*)(xb + i) = o;
    return;
  }
  __shared__ float tile[32][33];
  const float* in;
  short* out;
  int N, bx, by;
  if (bid < 11264) {
    int t = bid - 8192;
    in = wa; out = wat; N = 3072; bx = t % 96; by = t / 96;
  } else {
    int t = bid - 11264;
    in = wp; out = wpt; N = 1024; bx = t & 31; by = t >> 5;
  }
  int tx = tid & 31, ty = tid >> 5;  // 32 x 8
  int x0 = bx * 32, y0 = by * 32;
#pragma unroll
  for (int i = 0; i < 32; i += 8)
    tile[ty + i][tx] = in[(size_t)(y0 + ty + i) * N + x0 + tx];
  __syncthreads();
#pragma unroll
  for (int i = 0; i < 32; i += 8)
    out[(size_t)(x0 + ty + i) * 1024 + y0 + tx] = f2bf(tile[tx][ty + i]);
}

// ------------- legacy GEMM core (128x128, BK=32, 4 waves) — gemm_proj ------
#define GEMM_BODY(A_, Bt_)                                                        \
  __shared__ __align__(16) short As[128 * 32];                                    \
  __shared__ __align__(16) short Bs[128 * 32];                                    \
  const int tid = threadIdx.x;                                                    \
  const int wv = tid >> 6;                                                        \
  const int wr = wv >> 1, wc = wv & 1;                                            \
  const int col = tid & 31, khalf = (tid >> 5) & 1;                               \
  const int m0 = blockIdx.y * 128, n0 = blockIdx.x * 128;                         \
  f32x16 acc[2][2];                                                               \
  _Pragma("unroll") for (int i = 0; i < 2; ++i)                                   \
      _Pragma("unroll") for (int j = 0; j < 2; ++j)                               \
          acc[i][j] = (f32x16)(0.f);                                              \
  for (int k0 = 0; k0 < 1024; k0 += 32) {                                         \
    _Pragma("unroll") for (int i = 0; i < 2; ++i) {                               \
      int cc = tid + i * 256;                                                     \
      int row = cc >> 2, part = ((cc & 3) - ((cc >> 3) & 3)) & 3;                 \
      gl_lds16(A_ + (size_t)(m0 + row) * 1024 + k0 + part * 8,                    \
               (char*)As + cc * 16);                                              \
      gl_lds16(Bt_ + (size_t)(n0 + row) * 1024 + k0 + part * 8,                   \
               (char*)Bs + cc * 16);                                              \
    }                                                                             \
    __syncthreads();                                                              \
    short8 af[2][2], bf[2][2];                                                    \
    _Pragma("unroll") for (int i = 0; i < 2; ++i)                                 \
        _Pragma("unroll") for (int s = 0; s < 2; ++s) {                           \
          int pa = s * 2 + khalf;                                                 \
          int ra = wr * 64 + i * 32 + col;                                        \
          int rb = wc * 64 + i * 32 + col;                                        \
          af[i][s] = *(const short8*)&As[(ra * 4 + ((pa + (ra >> 1)) & 3)) * 8];  \
          bf[i][s] = *(const short8*)&Bs[(rb * 4 + ((pa + (rb >> 1)) & 3)) * 8];  \
        }                                                                         \
    _Pragma("unroll") for (int s = 0; s < 2; ++s)                                 \
        _Pragma("unroll") for (int i = 0; i < 2; ++i)                             \
            _Pragma("unroll") for (int j = 0; j < 2; ++j)                         \
                acc[i][j] = __builtin_amdgcn_mfma_f32_32x32x16_bf16(              \
                    af[i][s], bf[j][s], acc[i][j], 0, 0, 0);                      \
    __syncthreads();                                                              \
  }

__global__ __launch_bounds__(256, 2) void gemm_proj(
    const short* __restrict__ A, const short* __restrict__ Bt,
    const float* __restrict__ bias, float* __restrict__ out) {
  GEMM_BODY(A, Bt)
  const int rhalf = khalf * 4;
#pragma unroll
  for (int i = 0; i < 2; ++i) {
#pragma unroll
    for (int j = 0; j < 2; ++j) {
      int n = n0 + wc * 64 + j * 32 + col;
      float bv = bias[n];
      int mb = m0 + wr * 64 + i * 32 + rhalf;
#pragma unroll
      for (int a = 0; a < 16; ++a) {
        int m = mb + (a & 3) + 8 * (a >> 2);
        out[(size_t)m * 1024 + n] = acc[i][j][a] + bv;
      }
    }
  }
}

// ------------- QKV GEMM: 256x256 tile, BK=64, 8-phase counted-vmcnt --------
// LDS per buffer: A[2 ksub][256 rows][4 slots of 16B] bf16, B same.
// Rotation swizzle within each 64B row: slot (pa + (row>>1)) & 3 holds
// k-part pa. Read side: slot = (q4 + (ln16>>1)) & 3 (per-thread constant).
// Quarter-wave then covers all 8 bank groups twice = b128 floor.
// Phase p of tile kt: p0=(ks0,mh0) stage A(kt+1)ks1; p1=(ks0,mh1) stage
// B(kt+1)ks1; p2=(ks1,mh0) stage A(kt+2)ks0; p3=(ks1,mh1) stage B(kt+2)ks0.
// Boundary wait: vmcnt(4) (leaves the 2 newest half-tiles in flight);
// vmcnt(0) only entering the last tile.

#define LGKM0() asm volatile("s_waitcnt lgkmcnt(0)" ::: "memory")
#define BARRIER() asm volatile("s_barrier" ::: "memory")

#define STG(KT, S, SRC, LB)                                                \
  if ((KT) < 16) {                                                         \
    char* db_ = (char*)(LB) + (((KT) & 1) ? 32768 : 0) + ((S) * 16384);    \
    const short* sb_ = (SRC) + (KT) * 64 + (S) * 32;                       \
    gl_lds16(sb_ + g_off0, db_ + d_off0);                                  \
    gl_lds16(sb_ + g_off1, db_ + d_off1);                                  \
  }

#define LDA(S, MH)                                                         \
  _Pragma("unroll") for (int mt_ = 0; mt_ < 4; ++mt_)                      \
      af[mt_] = *(const short8*)(Ab + (S)*16384 + (MH)*4096 + arow_off +   \
                                 mt_ * 1024);

#define LDB(S)                                                             \
  _Pragma("unroll") for (int nt_ = 0; nt_ < 4; ++nt_)                      \
      bf[nt_] = *(const short8*)(Bb + (S)*16384 + brow_off + nt_ * 1024);

#define MFMA16(MH)                                                         \
  LGKM0();                                                                 \
  __builtin_amdgcn_sched_barrier(0);                                       \
  __builtin_amdgcn_s_setprio(1);                                           \
  _Pragma("unroll") for (int mt_ = 0; mt_ < 4; ++mt_)                      \
      _Pragma("unroll") for (int nt_ = 0; nt_ < 4; ++nt_)                  \
          acc[(MH)*4 + mt_][nt_] =                                         \
              __builtin_amdgcn_mfma_f32_16x16x32_bf16(                     \
                  af[mt_], bf[nt_], acc[(MH)*4 + mt_][nt_], 0, 0, 0);      \
  __builtin_amdgcn_s_setprio(0);

__global__ __launch_bounds__(512, 2) void gemm_qkv(
    const short* __restrict__ A, const short* __restrict__ Bt,
    const float* __restrict__ bias, short* __restrict__ Qb,
    short* __restrict__ Kb, short* __restrict__ Vtb) {
  __shared__ __align__(16) short Asm[2][16384];  // 64KB
  __shared__ __align__(16) short Bsm[2][16384];  // 64KB
  const int tid = threadIdx.x;
  const int wv = tid >> 6;               // 0..7
  const int wr = wv >> 2, wc = wv & 3;   // 2M x 4N waves
  const int ln16 = tid & 15, q4 = (tid >> 4) & 3;
  const int m0 = blockIdx.y * 256, n0 = blockIdx.x * 256;

  // staging: chunk cc = tid (+512); row = cc>>2, slot = cc&3 holds k-part
  // pa = ((cc&3) - ((cc>>3)&3)) & 3  (rotation swizzle, linear LDS dest)
  const int d_off0 = tid * 16, d_off1 = d_off0 + 8192;
  const int pa_st = ((tid & 3) - ((tid >> 3) & 3)) & 3;
  const size_t g_off0 = (size_t)(tid >> 2) * 1024 + (size_t)pa_st * 8;
  const size_t g_off1 = g_off0 + (size_t)128 * 1024;

  // fragment read offsets (bytes within a ksub region); rotated slot
  const int slot = (q4 + ((ln16 >> 1) & 3)) & 3;
  const int arow_off = (wr * 128 + ln16) * 64 + slot * 16;
  const int brow_off = (wc * 64 + ln16) * 64 + slot * 16;

  const short* srcA = A + (size_t)m0 * 1024;
  const short* srcB = Bt + (size_t)n0 * 1024;

  f32x4 acc[8][4];
#pragma unroll
  for (int i = 0; i < 8; ++i)
#pragma unroll
    for (int j = 0; j < 4; ++j) acc[i][j] = (f32x4){0.f, 0.f, 0.f, 0.f};

  // prologue: tile0 complete + tile1 ksub0 (tile1 ksub1 staged in tile0 p0/p1)
  STG(0, 0, srcA, Asm)
  STG(0, 0, srcB, Bsm)
  STG(0, 1, srcA, Asm)
  STG(0, 1, srcB, Bsm)
  STG(1, 0, srcA, Asm)
  STG(1, 0, srcB, Bsm)
  asm volatile("s_waitcnt vmcnt(4)" ::: "memory");
  BARRIER();

  for (int kt = 0; kt < 16; ++kt) {
    const char* Ab = (const char*)Asm + ((kt & 1) ? 32768 : 0);
    const char* Bb = (const char*)Bsm + ((kt & 1) ? 32768 : 0);
    short8 af[4], bf[4];
    // phase 0: ksub0, mhalf0
    LDB(0)
    LDA(0, 0)
    STG(kt + 1, 1, srcA, Asm)
    BARRIER();
    MFMA16(0)
    BARRIER();
    // phase 1: ksub0, mhalf1 (reuse bf)
    LDA(0, 1)
    STG(kt + 1, 1, srcB, Bsm)
    BARRIER();
    MFMA16(1)
    BARRIER();
    // phase 2: ksub1, mhalf0
    LDB(1)
    LDA(1, 0)
    STG(kt + 2, 0, srcA, Asm)
    BARRIER();
    MFMA16(0)
    BARRIER();
    // phase 3: ksub1, mhalf1
    LDA(1, 1)
    STG(kt + 2, 0, srcB, Bsm)
    BARRIER();
    MFMA16(1)
    // K-tile boundary: counted wait, never 0 in steady state
    if (kt == 14) {
      asm volatile("s_waitcnt vmcnt(0)" ::: "memory");
    } else {
      asm volatile("s_waitcnt vmcnt(4)" ::: "memory");
    }
    BARRIER();
  }

  // epilogue: C/D map per 16x16 tile: n_local = lane&15, m_local = q4*4 + r
  // acc[i][nt]: rowbase = (i>>2)*64 + (i&3)*16
#pragma unroll
  for (int nt = 0; nt < 4; ++nt) {
    int n = n0 + wc * 64 + nt * 16 + ln16;
    float bv = bias[n];
    int n2 = n & 1023;
    int hcol = n2 >> 6, d = n2 & 63;
#pragma unroll
    for (int i = 0; i < 8; ++i) {
      int mb = m0 + wr * 128 + (i >> 2) * 64 + (i & 3) * 16 + q4 * 4;
      int bh = ((mb >> 11) << 4) + hcol;
      if (n < 2048) {  // Q or K: [bh][t][d], scalar b16 stores
        const bool isq = n < 1024;
#pragma unroll
        for (int r = 0; r < 4; ++r) {
          int t = (mb + r) & 2047;
          float o = acc[i][nt][r] + bv;
          size_t idx = ((size_t)bh * 2048 + t) * 64 + d;
          if (isq)
            Qb[idx] = f2bf(o * 0.18033688f);
          else
            Kb[idx] = f2bf(o);
        }
      } else {  // V^T: [bh][d][t], b64 store over the 4 consecutive t
        int t = mb & 2047;
        short4v o;
#pragma unroll
        for (int r = 0; r < 4; ++r) o[r] = f2bf(acc[i][nt][r] + bv);
        *(short4v*)&Vtb[((size_t)bh * 64 + d) * 2048 + t] = o;
      }
    }
  }
}

// ---------------- flash attention (R10 version — kept) ----------------------
__global__ __launch_bounds__(256, 2) void flash_attn(
    const short* __restrict__ Qg_, const short* __restrict__ Kg_,
    const short* __restrict__ Vg_, short* __restrict__ Ob) {
  constexpr int STR = 72;  // padded rows: rotates bank window 4/row
  __shared__ __align__(16) short Kl[2][64 * STR];
  __shared__ __align__(16) short Vl[2][64 * STR];
  const int tid = threadIdx.x;
  const int wv = tid >> 6, ln = tid & 15, quad = (tid & 63) >> 4;
  const int bh = blockIdx.x & 63;
  const int pair = blockIdx.x >> 6;
  const short* Qg = Qg_ + (size_t)bh * 2048 * 64;
  const short* Kg = Kg_ + (size_t)bh * 2048 * 64;
  const short* Vg = Vg_ + (size_t)bh * 64 * 2048;
  const int srow = tid >> 3, spart = tid & 7;
  const int bb = bh >> 4, hh = bh & 15;

  short8 kreg[2], vreg[2];

#define LOADKV(KT)                                                              \
  {                                                                             \
    const short* Kt = Kg + (size_t)(KT) * 64 * 64;                              \
    _Pragma("unroll") for (int i = 0; i < 2; ++i) {                             \
      kreg[i] = *(const short8*)(Kt + (size_t)(srow + i * 32) * 64 + spart * 8);\
      vreg[i] = *(const short8*)(Vg + (size_t)(srow + i * 32) * 2048 +          \
                                 (KT) * 64 + spart * 8);                        \
    }                                                                           \
  }
#define WRITEKV(BUF)                                                            \
  _Pragma("unroll") for (int i = 0; i < 2; ++i) {                               \
    *(short8*)&Kl[BUF][(srow + i * 32) * STR + spart * 8] = kreg[i];            \
    *(short8*)&Vl[BUF][(srow + i * 32) * STR + spart * 8] = vreg[i];            \
  }

#pragma unroll
  for (int it = 0; it < 2; ++it) {
    const int qt = it ? pair : (15 - pair);  // long item first
    const int q0 = qt * 128;
    const int qbase = q0 + wv * 32;
    const int nkt = (q0 >> 6) + 2;

    short8 qf[2][2];
#pragma unroll
    for (int h = 0; h < 2; ++h)
#pragma unroll
      for (int ch = 0; ch < 2; ++ch)
        qf[h][ch] = *(const short8*)(Qg + (size_t)(qbase + h * 16 + ln) * 64 +
                                     ch * 32 + quad * 8);

    f32x4 Oacc[2][4];
#pragma unroll
    for (int h = 0; h < 2; ++h)
#pragma unroll
      for (int mt = 0; mt < 4; ++mt) Oacc[h][mt] = (f32x4){0.f, 0.f, 0.f, 0.f};
    float lpart[2] = {0.f, 0.f};

    LOADKV(0)
    __syncthreads();  // previous item's readers of buf0 done
    WRITEKV(0)
    LOADKV(1)

    for (int kt = 0; kt < nkt; ++kt) {
      __syncthreads();  // buf[kt&1] staged; prev readers of buf[(kt+1)&1] done
      const short* Kcur = Kl[kt & 1];
      const short* Vcur = Vl[kt & 1];
      if (kt + 1 < nkt) {
        WRITEKV((kt + 1) & 1)  // overlaps this iter's compute reads
        if (kt + 2 < nkt) LOADKV(kt + 2)
      }

      if (kt * 64 <= qbase + 31) {  // wave-uniform skip of fully-masked tiles
        f32x4 St[2][4];
#pragma unroll
        for (int h = 0; h < 2; ++h)
#pragma unroll
          for (int kb = 0; kb < 4; ++kb) St[h][kb] = (f32x4){0.f, 0.f, 0.f, 0.f};
#pragma unroll
        for (int kb = 0; kb < 4; ++kb) {
          short8 ka0 = *(const short8*)&Kcur[(kb * 16 + ln) * STR + quad * 8];
          short8 ka1 = *(const short8*)&Kcur[(kb * 16 + ln) * STR + 32 + quad * 8];
#pragma unroll
          for (int h = 0; h < 2; ++h) {
            St[h][kb] = __builtin_amdgcn_mfma_f32_16x16x32_bf16(
                ka0, qf[h][0], St[h][kb], 0, 0, 0);
            St[h][kb] = __builtin_amdgcn_mfma_f32_16x16x32_bf16(
                ka1, qf[h][1], St[h][kb], 0, 0, 0);
          }
        }

        // p = exp2(s); l partials; pack. Mask only on the diagonal tile
        // (wave-uniform branch; ~6% of iters).
        short4v pf[2][4];
#pragma unroll
        for (int h = 0; h < 2; ++h) {
          float lp0 = 0.f, lp1 = 0.f;
          if (kt * 64 + 63 <= qbase + h * 16) {  // fully unmasked
#pragma unroll
            for (int kb = 0; kb < 4; ++kb) {
              float p[4];
#pragma unroll
              for (int r = 0; r < 4; ++r)
                p[r] = __builtin_amdgcn_exp2f(St[h][kb][r]);
              lp0 += p[0] + p[2];
              lp1 += p[1] + p[3];
              union { __hip_bfloat162 b2; unsigned u; } w0, w1;
              w0.b2 = __float22bfloat162_rn(make_float2(p[0], p[1]));
              w1.b2 = __float22bfloat162_rn(make_float2(p[2], p[3]));
              union { short4v s4; unsigned u2[2]; } m;
              m.u2[0] = w0.u; m.u2[1] = w1.u;
              pf[h][kb] = m.s4;
            }
          } else {  // diagonal tile: per-element causal mask
            const int qg = qbase + h * 16 + ln;
#pragma unroll
            for (int kb = 0; kb < 4; ++kb) {
              float p[4];
#pragma unroll
              for (int r = 0; r < 4; ++r) {
                int key = kt * 64 + kb * 16 + quad * 4 + r;
                float s = (key <= qg) ? St[h][kb][r] : -1e30f;
                p[r] = __builtin_amdgcn_exp2f(s);
              }
              lp0 += p[0] + p[2];
              lp1 += p[1] + p[3];
              union { __hip_bfloat162 b2; unsigned u; } w0, w1;
              w0.b2 = __float22bfloat162_rn(make_float2(p[0], p[1]));
              w1.b2 = __float22bfloat162_rn(make_float2(p[2], p[3]));
              union { short4v s4; unsigned u2[2]; } m;
              m.u2[0] = w0.u; m.u2[1] = w1.u;
              pf[h][kb] = m.s4;
            }
          }
          lpart[h] += lp0 + lp1;
        }

#pragma unroll
        for (int kb = 0; kb < 4; ++kb)
#pragma unroll
          for (int mt = 0; mt < 4; ++mt) {
            short4v va =
                *(const short4v*)&Vcur[(mt * 16 + ln) * STR + kb * 16 + quad * 4];
#pragma unroll
            for (int h = 0; h < 2; ++h)
              Oacc[h][mt] = __builtin_amdgcn_mfma_f32_16x16x16bf16_1k(
                  va, pf[h][kb], Oacc[h][mt], 0, 0, 0);
          }
      }
    }

#pragma unroll
    for (int h = 0; h < 2; ++h) {
      float l = lpart[h];
      l += __shfl_xor(l, 16);
      l += __shfl_xor(l, 32);
      float rl = 1.0f / l;
      int t = qbase + h * 16 + ln;
#pragma unroll
      for (int mt = 0; mt < 4; ++mt) {
        short4v o;
#pragma unroll
        for (int r = 0; r < 4; ++r) o[r] = f2bf(Oacc[h][mt][r] * rl);
        *(short4v*)(Ob + ((size_t)(bb * 2048 + t)) * 1024 + hh * 64 + mt * 16 +
                    quad * 4) = o;
      }
    }
  }
#undef LOADKV
#undef WRITEKV
}

// ---------------- launcher ----------------

extern "C" void kernel_launch(void* const* d_in, const int* in_sizes, int n_in,
                              void* d_out, int out_size, void* d_ws, size_t ws_size,
                              hipStream_t stream) {
  const float* x      = (const float*)d_in[0];
  const float* w_attn = (const float*)d_in[1];
  const float* b_attn = (const float*)d_in[2];
  const float* w_proj = (const float*)d_in[3];
  const float* b_proj = (const float*)d_in[4];
  float* out = (float*)d_out;
  char* ws = (char*)d_ws;

  short* xb  = (short*)(ws);
  short* wat = (short*)(ws + 16777216);
  short* wpt = (short*)(ws + 23068672);
  short* Qb  = (short*)(ws + 25165824);
  short* Kb  = (short*)(ws + 41943040);
  short* Vtb = (short*)(ws + 58720256);
  short* Ob  = (short*)(ws + 75497472);

  prep<<<12288, 256, 0, stream>>>(x, w_attn, w_proj, xb, wat, wpt);
  gemm_qkv<<<dim3(12, 32), 512, 0, stream>>>(xb, wat, b_attn, Qb, Kb, Vtb);
  flash_attn<<<512, 256, 0, stream>>>(Qb, Kb, Vtb, Ob);
  gemm_proj<<<dim3(8, 64), 256, 0, stream>>>(Ob, wpt, b_proj, out);
}

// Round 4
// 255.255 us; speedup vs baseline: 1.0374x; 1.0235x over previous
//
#include <hip/hip_runtime.h>
#include <hip/hip_bf16.h>

// CausalSelfAttention: B=4 T=2048 C=1024 H=16 D=64
// ws layout (bytes):
//   xb   @ 0         : x as bf16           [8192][1024]   16 MB
//   wat  @ 16777216  : w_attn^T bf16       [3072][1024]    6 MB
//   wpt  @ 23068672  : w_proj^T bf16       [1024][1024]    2 MB
//   Qb   @ 25165824  : Q bf16 (pre-scaled by 0.125*log2e) [B,H,T,D] 16 MB
//   Kb   @ 41943040  : K bf16  [B,H,T,D]                  16 MB
//   Vtb  @ 58720256  : V^T bf16 [B,H,D,T]  (written directly by gemm_qkv)
//   Ob   @ 75497472  : attn out bf16 [8192][1024]         16 MB
//
// R15 = R14 resubmitted after infra failure ("container failed twice"; prior
// round showed 410s npz pushes). Full audit found no hang/fault path:
// uniform barriers, waitcnt invariants re-derived per-load, WAR on LDS
// staging closed by P(n+1)'s lgkmcnt(6) before the P(n+1)-end barrier,
// all STG guarded, ~200 VGPR under the 1-block/CU 256 budget.
//
// R14 design: gemm_qkv restructured for LDS/MFMA overlap. R13 post-mortem:
// phase = 620 cyc MFMA + 576 cyc LDS drain run SERIALLY (lgkmcnt(0) waits on
// same-phase reads) = 1660 cyc/phase. Fix: fragment reads issued ONE PHASE
// AHEAD into a double-buffered register set; MFMA waits counted lgkmcnt(6)
// (drains only prev-phase reads, already serviced during the MFMA cluster).
// 32x32x16 MFMA (24 VGPR/frag-set vs 40 for 16x16 -> doubled sets fit; also
// ~15% better pipe efficiency). One barrier per phase; vmcnt(6) at P0/P2
// ends (tails: kt=14 vmcnt(4), kt=15 vmcnt(0)). Rotation swizzle kept
// (R13: conflicts = 0).

typedef float f32x4 __attribute__((ext_vector_type(4)));
typedef float f32x16 __attribute__((ext_vector_type(16)));
typedef short short8 __attribute__((ext_vector_type(8)));
typedef short short4v __attribute__((ext_vector_type(4)));

__device__ __forceinline__ short f2bf(float f) {
  union { __hip_bfloat16 h; short s; } u;
  u.h = __float2bfloat16(f);
  return u.s;
}

__device__ __forceinline__ void gl_lds16(const void* g, void* l) {
  __builtin_amdgcn_global_load_lds(
      (const __attribute__((address_space(1))) void*)g,
      (__attribute__((address_space(3))) void*)l, 16, 0, 0);
}

// ---------------- fused prep: x cvt + w_attn^T + w_proj^T -------------------
__global__ void prep(const float* __restrict__ x, const float* __restrict__ wa,
                     const float* __restrict__ wp, short* __restrict__ xb,
                     short* __restrict__ wat, short* __restrict__ wpt) {
  const int bid = blockIdx.x, tid = threadIdx.x;
  if (bid < 8192) {
    int i = (bid * 256 + tid) * 4;
    float4 v = *(const float4*)(x + i);
    short4v o;
    o[0] = f2bf(v.x); o[1] = f2bf(v.y); o[2] = f2bf(v.z); o[3] = f2bf(v.w);
    *(short4v*)(xb + i) = o;
    return;
  }
  __shared__ float tile[32][33];
  const float* in;
  short* out;
  int N, bx, by;
  if (bid < 11264) {
    int t = bid - 8192;
    in = wa; out = wat; N = 3072; bx = t % 96; by = t / 96;
  } else {
    int t = bid - 11264;
    in = wp; out = wpt; N = 1024; bx = t & 31; by = t >> 5;
  }
  int tx = tid & 31, ty = tid >> 5;  // 32 x 8
  int x0 = bx * 32, y0 = by * 32;
#pragma unroll
  for (int i = 0; i < 32; i += 8)
    tile[ty + i][tx] = in[(size_t)(y0 + ty + i) * N + x0 + tx];
  __syncthreads();
#pragma unroll
  for (int i = 0; i < 32; i += 8)
    out[(size_t)(x0 + ty + i) * 1024 + y0 + tx] = f2bf(tile[tx][ty + i]);
}

// ------------- legacy GEMM core (128x128, BK=32, 4 waves) — gemm_proj ------
#define GEMM_BODY(A_, Bt_)                                                        \
  __shared__ __align__(16) short As[128 * 32];                                    \
  __shared__ __align__(16) short Bs[128 * 32];                                    \
  const int tid = threadIdx.x;                                                    \
  const int wv = tid >> 6;                                                        \
  const int wr = wv >> 1, wc = wv & 1;                                            \
  const int col = tid & 31, khalf = (tid >> 5) & 1;                               \
  const int m0 = blockIdx.y * 128, n0 = blockIdx.x * 128;                         \
  f32x16 acc[2][2];                                                               \
  _Pragma("unroll") for (int i = 0; i < 2; ++i)                                   \
      _Pragma("unroll") for (int j = 0; j < 2; ++j)                               \
          acc[i][j] = (f32x16)(0.f);                                              \
  for (int k0 = 0; k0 < 1024; k0 += 32) {                                         \
    _Pragma("unroll") for (int i = 0; i < 2; ++i) {                               \
      int cc = tid + i * 256;                                                     \
      int row = cc >> 2, part = ((cc & 3) - ((cc >> 3) & 3)) & 3;                 \
      gl_lds16(A_ + (size_t)(m0 + row) * 1024 + k0 + part * 8,                    \
               (char*)As + cc * 16);                                              \
      gl_lds16(Bt_ + (size_t)(n0 + row) * 1024 + k0 + part * 8,                   \
               (char*)Bs + cc * 16);                                              \
    }                                                                             \
    __syncthreads();                                                              \
    short8 af[2][2], bf[2][2];                                                    \
    _Pragma("unroll") for (int i = 0; i < 2; ++i)                                 \
        _Pragma("unroll") for (int s = 0; s < 2; ++s) {                           \
          int pa = s * 2 + khalf;                                                 \
          int ra = wr * 64 + i * 32 + col;                                        \
          int rb = wc * 64 + i * 32 + col;                                        \
          af[i][s] = *(const short8*)&As[(ra * 4 + ((pa + (ra >> 1)) & 3)) * 8];  \
          bf[i][s] = *(const short8*)&Bs[(rb * 4 + ((pa + (rb >> 1)) & 3)) * 8];  \
        }                                                                         \
    _Pragma("unroll") for (int s = 0; s < 2; ++s)                                 \
        _Pragma("unroll") for (int i = 0; i < 2; ++i)                             \
            _Pragma("unroll") for (int j = 0; j < 2; ++j)                         \
                acc[i][j] = __builtin_amdgcn_mfma_f32_32x32x16_bf16(              \
                    af[i][s], bf[j][s], acc[i][j], 0, 0, 0);                      \
    __syncthreads();                                                              \
  }

__global__ __launch_bounds__(256, 2) void gemm_proj(
    const short* __restrict__ A, const short* __restrict__ Bt,
    const float* __restrict__ bias, float* __restrict__ out) {
  GEMM_BODY(A, Bt)
  const int rhalf = khalf * 4;
#pragma unroll
  for (int i = 0; i < 2; ++i) {
#pragma unroll
    for (int j = 0; j < 2; ++j) {
      int n = n0 + wc * 64 + j * 32 + col;
      float bv = bias[n];
      int mb = m0 + wr * 64 + i * 32 + rhalf;
#pragma unroll
      for (int a = 0; a < 16; ++a) {
        int m = mb + (a & 3) + 8 * (a >> 2);
        out[(size_t)m * 1024 + n] = acc[i][j][a] + bv;
      }
    }
  }
}

// ------------- QKV GEMM: 256x256, BK=64, 32x32x16, reg-prefetch pipeline ---
// LDS per buffer: [2 ksub][256 rows][4 slots x 16B]; rotation swizzle: slot
// (pa + (row>>1))&3 holds k-part pa (staged via pre-swizzled global source,
// linear LDS dest). Frag read slot = ((kk&1)*2 + khalf + (ln32>>1)) & 3 —
// per-thread constant per kstep parity. Quarter-wave covers 8 distinct 16B
// positions x 2 lanes = 2-way = free (m136; R13 measured 0 conflicts).
// Phase p (kstep p of the kt tile): issue 6 ds_reads for kstep p+1 into the
// alternate reg set + 1 STG pair; counted lgkmcnt(6) (drains phase p-1's
// reads, serviced during the previous MFMA cluster); 8 MFMA; barrier.
// STG schedule: P0/P1 stage (kt+1)ks1 A/B; P2/P3 stage (kt+2)ks0 A/B.
// vmcnt(6)@P0-end guarantees (kt)ks1 staged; vmcnt(6)@P2-end guarantees
// (kt+1)ks0 staged. Tails: kt=14 P2-end vmcnt(4); kt=15 P0-end vmcnt(0),
// P3 issues no reads (lgkmcnt(0)).

#define BARRIER() asm volatile("s_barrier" ::: "memory")
#define VMC(N) asm volatile("s_waitcnt vmcnt(" #N ")" ::: "memory")

#define STG(KT, S, SRC, LB)                                                \
  if ((KT) < 16) {                                                         \
    char* db_ = (char*)(LB) + (((KT) & 1) ? 32768 : 0) + ((S) * 16384);    \
    const short* sb_ = (SRC) + (KT) * 64 + (S) * 32;                       \
    gl_lds16(sb_ + g_off0, db_ + d_off0);                                  \
    gl_lds16(sb_ + g_off1, db_ + d_off1);                                  \
  }

// 6 ds_read_b128: 4 A-frags + 2 B-frags for one 16-wide kstep.
#define LDF(AF, BF, ABP, BBP, S, AO, BO)                                   \
  _Pragma("unroll") for (int mt_ = 0; mt_ < 4; ++mt_)                      \
      AF[mt_] = *(const short8*)((ABP) + (S) * 16384 + (AO)[mt_]);         \
  _Pragma("unroll") for (int nt_ = 0; nt_ < 2; ++nt_)                      \
      BF[nt_] = *(const short8*)((BBP) + (S) * 16384 + (BO)[nt_]);

#define MFMA8_BODY(AF, BF)                                                 \
  __builtin_amdgcn_sched_barrier(0);                                       \
  __builtin_amdgcn_s_setprio(1);                                           \
  _Pragma("unroll") for (int mt_ = 0; mt_ < 4; ++mt_)                      \
      _Pragma("unroll") for (int nt_ = 0; nt_ < 2; ++nt_)                  \
          acc[mt_][nt_] = __builtin_amdgcn_mfma_f32_32x32x16_bf16(         \
              AF[mt_], BF[nt_], acc[mt_][nt_], 0, 0, 0);                   \
  __builtin_amdgcn_s_setprio(0);

#define MFMA8(AF, BF)                                                      \
  __builtin_amdgcn_sched_barrier(0);                                       \
  asm volatile("s_waitcnt lgkmcnt(6)" ::: "memory");                       \
  MFMA8_BODY(AF, BF)

#define MFMA8_LG0(AF, BF)                                                  \
  __builtin_amdgcn_sched_barrier(0);                                       \
  asm volatile("s_waitcnt lgkmcnt(0)" ::: "memory");                       \
  MFMA8_BODY(AF, BF)

__global__ __launch_bounds__(512, 2) void gemm_qkv(
    const short* __restrict__ A, const short* __restrict__ Bt,
    const float* __restrict__ bias, short* __restrict__ Qb,
    short* __restrict__ Kb, short* __restrict__ Vtb) {
  __shared__ __align__(16) short Asm[2][16384];  // 64KB
  __shared__ __align__(16) short Bsm[2][16384];  // 64KB
  const int tid = threadIdx.x;
  const int wv = tid >> 6;               // 0..7
  const int wr = wv >> 2, wc = wv & 3;   // 2M x 4N waves; wave tile 128x64
  const int ln32 = tid & 31, khalf = (tid >> 5) & 1;
  const int m0 = blockIdx.y * 256, n0 = blockIdx.x * 256;

  // staging: chunk cc = tid (+512); row = cc>>2; slot cc&3 holds k-part
  // pa = ((cc&3) - (row>>1)) & 3  (rotation swizzle, linear LDS dest)
  const int d_off0 = tid * 16, d_off1 = d_off0 + 8192;
  const int pa_st = ((tid & 3) - ((tid >> 3) & 3)) & 3;
  const size_t g_off0 = (size_t)(tid >> 2) * 1024 + (size_t)pa_st * 8;
  const size_t g_off1 = g_off0 + (size_t)128 * 1024;

  // fragment read byte-offsets within a ksub region (row*64 + slot*16)
  const int rot = (ln32 >> 1) & 3;
  const int slotE = (khalf + rot) & 3;        // kstep even: pa = khalf
  const int slotO = (2 + khalf + rot) & 3;    // kstep odd:  pa = 2 + khalf
  int aoffE[4], aoffO[4], boffE[2], boffO[2];
#pragma unroll
  for (int mt = 0; mt < 4; ++mt) {
    int r = (wr * 128 + mt * 32 + ln32) * 64;
    aoffE[mt] = r + slotE * 16;
    aoffO[mt] = r + slotO * 16;
  }
#pragma unroll
  for (int nt = 0; nt < 2; ++nt) {
    int r = (wc * 64 + nt * 32 + ln32) * 64;
    boffE[nt] = r + slotE * 16;
    boffO[nt] = r + slotO * 16;
  }

  const short* srcA = A + (size_t)m0 * 1024;
  const short* srcB = Bt + (size_t)n0 * 1024;

  f32x16 acc[4][2];
#pragma unroll
  for (int i = 0; i < 4; ++i)
#pragma unroll
    for (int j = 0; j < 2; ++j) acc[i][j] = (f32x16)(0.f);

  short8 af0[4], af1[4], bf0[2], bf1[2];

  // prologue: stage tile0 (ks0+ks1) + tile1 ks0; wait tile0 ks0; read kstep0
  STG(0, 0, srcA, Asm)
  STG(0, 0, srcB, Bsm)
  STG(0, 1, srcA, Asm)
  STG(0, 1, srcB, Bsm)
  STG(1, 0, srcA, Asm)
  STG(1, 0, srcB, Bsm)
  VMC(8);
  BARRIER();
  {
    const char* Ab0 = (const char*)Asm;
    const char* Bb0 = (const char*)Bsm;
    LDF(af0, bf0, Ab0, Bb0, 0, aoffE, boffE)
  }

  for (int kt = 0; kt < 16; ++kt) {
    const char* Ab = (const char*)Asm + ((kt & 1) << 15);
    const char* Bb = (const char*)Bsm + ((kt & 1) << 15);
    const char* An = (const char*)Asm + (((kt + 1) & 1) << 15);
    const char* Bn = (const char*)Bsm + (((kt + 1) & 1) << 15);
    // P0: consume set0 (kstep0); prefetch kstep1 -> set1
    LDF(af1, bf1, Ab, Bb, 0, aoffO, boffO)
    STG(kt + 1, 1, srcA, Asm)
    MFMA8(af0, bf0)
    if (kt == 15) { VMC(0); } else { VMC(6); }
    BARRIER();
    // P1: consume set1 (kstep1); prefetch kstep2 -> set0
    LDF(af0, bf0, Ab, Bb, 1, aoffE, boffE)
    STG(kt + 1, 1, srcB, Bsm)
    MFMA8(af1, bf1)
    BARRIER();
    // P2: consume set0 (kstep2); prefetch kstep3 -> set1
    LDF(af1, bf1, Ab, Bb, 1, aoffO, boffO)
    STG(kt + 2, 0, srcA, Asm)
    MFMA8(af0, bf0)
    if (kt == 14) { VMC(4); } else if (kt < 14) { VMC(6); }
    BARRIER();
    // P3: consume set1 (kstep3); prefetch next tile kstep0 -> set0
    if (kt < 15) {
      LDF(af0, bf0, An, Bn, 0, aoffE, boffE)
      STG(kt + 2, 0, srcB, Bsm)
      MFMA8(af1, bf1)
    } else {
      MFMA8_LG0(af1, bf1)
    }
    BARRIER();
  }

  // epilogue: 32x32 C/D map: col = lane&31 -> n; row = (a&3)+8*(a>>2)+4*khalf
  const int col = tid & 31;
  const int rhalf = khalf * 4;
#pragma unroll
  for (int i = 0; i < 4; ++i) {
#pragma unroll
    for (int j = 0; j < 2; ++j) {
      int n = n0 + wc * 64 + j * 32 + col;
      int n2 = n & 1023;
      int hh = n2 >> 6, d = n2 & 63;
      float bv = bias[n];
      int mb = m0 + wr * 128 + i * 32 + rhalf;
      int bb = mb >> 11;
      int bh = (bb << 4) + hh;
      if (n < 2048) {  // Q or K: [bh][t][d], scalar b16 stores
        const bool isq = n < 1024;
#pragma unroll
        for (int a = 0; a < 16; ++a) {
          int t = (mb + (a & 3) + 8 * (a >> 2)) & 2047;
          float o = acc[i][j][a] + bv;
          size_t idx = ((size_t)bh * 2048 + t) * 64 + d;
          if (isq)
            Qb[idx] = f2bf(o * 0.18033688f);
          else
            Kb[idx] = f2bf(o);
        }
      } else {  // V^T: [bh][d][t], b64 stores over reg groups
#pragma unroll
        for (int g = 0; g < 4; ++g) {
          int t = (mb + 8 * g) & 2047;
          short4v o;
#pragma unroll
          for (int r = 0; r < 4; ++r) o[r] = f2bf(acc[i][j][g * 4 + r] + bv);
          *(short4v*)&Vtb[((size_t)bh * 64 + d) * 2048 + t] = o;
        }
      }
    }
  }
}

// ---------------- flash attention (R10 version — kept) ----------------------
__global__ __launch_bounds__(256, 2) void flash_attn(
    const short* __restrict__ Qg_, const short* __restrict__ Kg_,
    const short* __restrict__ Vg_, short* __restrict__ Ob) {
  constexpr int STR = 72;  // padded rows: rotates bank window 4/row
  __shared__ __align__(16) short Kl[2][64 * STR];
  __shared__ __align__(16) short Vl[2][64 * STR];
  const int tid = threadIdx.x;
  const int wv = tid >> 6, ln = tid & 15, quad = (tid & 63) >> 4;
  const int bh = blockIdx.x & 63;
  const int pair = blockIdx.x >> 6;
  const short* Qg = Qg_ + (size_t)bh * 2048 * 64;
  const short* Kg = Kg_ + (size_t)bh * 2048 * 64;
  const short* Vg = Vg_ + (size_t)bh * 64 * 2048;
  const int srow = tid >> 3, spart = tid & 7;
  const int bb = bh >> 4, hh = bh & 15;

  short8 kreg[2], vreg[2];

#define LOADKV(KT)                                                              \
  {                                                                             \
    const short* Kt = Kg + (size_t)(KT) * 64 * 64;                              \
    _Pragma("unroll") for (int i = 0; i < 2; ++i) {                             \
      kreg[i] = *(const short8*)(Kt + (size_t)(srow + i * 32) * 64 + spart * 8);\
      vreg[i] = *(const short8*)(Vg + (size_t)(srow + i * 32) * 2048 +          \
                                 (KT) * 64 + spart * 8);                        \
    }                                                                           \
  }
#define WRITEKV(BUF)                                                            \
  _Pragma("unroll") for (int i = 0; i < 2; ++i) {                               \
    *(short8*)&Kl[BUF][(srow + i * 32) * STR + spart * 8] = kreg[i];            \
    *(short8*)&Vl[BUF][(srow + i * 32) * STR + spart * 8] = vreg[i];            \
  }

#pragma unroll
  for (int it = 0; it < 2; ++it) {
    const int qt = it ? pair : (15 - pair);  // long item first
    const int q0 = qt * 128;
    const int qbase = q0 + wv * 32;
    const int nkt = (q0 >> 6) + 2;

    short8 qf[2][2];
#pragma unroll
    for (int h = 0; h < 2; ++h)
#pragma unroll
      for (int ch = 0; ch < 2; ++ch)
        qf[h][ch] = *(const short8*)(Qg + (size_t)(qbase + h * 16 + ln) * 64 +
                                     ch * 32 + quad * 8);

    f32x4 Oacc[2][4];
#pragma unroll
    for (int h = 0; h < 2; ++h)
#pragma unroll
      for (int mt = 0; mt < 4; ++mt) Oacc[h][mt] = (f32x4){0.f, 0.f, 0.f, 0.f};
    float lpart[2] = {0.f, 0.f};

    LOADKV(0)
    __syncthreads();  // previous item's readers of buf0 done
    WRITEKV(0)
    LOADKV(1)

    for (int kt = 0; kt < nkt; ++kt) {
      __syncthreads();  // buf[kt&1] staged; prev readers of buf[(kt+1)&1] done
      const short* Kcur = Kl[kt & 1];
      const short* Vcur = Vl[kt & 1];
      if (kt + 1 < nkt) {
        WRITEKV((kt + 1) & 1)  // overlaps this iter's compute reads
        if (kt + 2 < nkt) LOADKV(kt + 2)
      }

      if (kt * 64 <= qbase + 31) {  // wave-uniform skip of fully-masked tiles
        f32x4 St[2][4];
#pragma unroll
        for (int h = 0; h < 2; ++h)
#pragma unroll
          for (int kb = 0; kb < 4; ++kb) St[h][kb] = (f32x4){0.f, 0.f, 0.f, 0.f};
#pragma unroll
        for (int kb = 0; kb < 4; ++kb) {
          short8 ka0 = *(const short8*)&Kcur[(kb * 16 + ln) * STR + quad * 8];
          short8 ka1 = *(const short8*)&Kcur[(kb * 16 + ln) * STR + 32 + quad * 8];
#pragma unroll
          for (int h = 0; h < 2; ++h) {
            St[h][kb] = __builtin_amdgcn_mfma_f32_16x16x32_bf16(
                ka0, qf[h][0], St[h][kb], 0, 0, 0);
            St[h][kb] = __builtin_amdgcn_mfma_f32_16x16x32_bf16(
                ka1, qf[h][1], St[h][kb], 0, 0, 0);
          }
        }

        // p = exp2(s); l partials; pack. Mask only on the diagonal tile
        // (wave-uniform branch; ~6% of iters).
        short4v pf[2][4];
#pragma unroll
        for (int h = 0; h < 2; ++h) {
          float lp0 = 0.f, lp1 = 0.f;
          if (kt * 64 + 63 <= qbase + h * 16) {  // fully unmasked
#pragma unroll
            for (int kb = 0; kb < 4; ++kb) {
              float p[4];
#pragma unroll
              for (int r = 0; r < 4; ++r)
                p[r] = __builtin_amdgcn_exp2f(St[h][kb][r]);
              lp0 += p[0] + p[2];
              lp1 += p[1] + p[3];
              union { __hip_bfloat162 b2; unsigned u; } w0, w1;
              w0.b2 = __float22bfloat162_rn(make_float2(p[0], p[1]));
              w1.b2 = __float22bfloat162_rn(make_float2(p[2], p[3]));
              union { short4v s4; unsigned u2[2]; } m;
              m.u2[0] = w0.u; m.u2[1] = w1.u;
              pf[h][kb] = m.s4;
            }
          } else {  // diagonal tile: per-element causal mask
            const int qg = qbase + h * 16 + ln;
#pragma unroll
            for (int kb = 0; kb < 4; ++kb) {
              float p[4];
#pragma unroll
              for (int r = 0; r < 4; ++r) {
                int key = kt * 64 + kb * 16 + quad * 4 + r;
                float s = (key <= qg) ? St[h][kb][r] : -1e30f;
                p[r] = __builtin_amdgcn_exp2f(s);
              }
              lp0 += p[0] + p[2];
              lp1 += p[1] + p[3];
              union { __hip_bfloat162 b2; unsigned u; } w0, w1;
              w0.b2 = __float22bfloat162_rn(make_float2(p[0], p[1]));
              w1.b2 = __float22bfloat162_rn(make_float2(p[2], p[3]));
              union { short4v s4; unsigned u2[2]; } m;
              m.u2[0] = w0.u; m.u2[1] = w1.u;
              pf[h][kb] = m.s4;
            }
          }
          lpart[h] += lp0 + lp1;
        }

#pragma unroll
        for (int kb = 0; kb < 4; ++kb)
#pragma unroll
          for (int mt = 0; mt < 4; ++mt) {
            short4v va =
                *(const short4v*)&Vcur[(mt * 16 + ln) * STR + kb * 16 + quad * 4];
#pragma unroll
            for (int h = 0; h < 2; ++h)
              Oacc[h][mt] = __builtin_amdgcn_mfma_f32_16x16x16bf16_1k(
                  va, pf[h][kb], Oacc[h][mt], 0, 0, 0);
          }
      }
    }

#pragma unroll
    for (int h = 0; h < 2; ++h) {
      float l = lpart[h];
      l += __shfl_xor(l, 16);
      l += __shfl_xor(l, 32);
      float rl = 1.0f / l;
      int t = qbase + h * 16 + ln;
#pragma unroll
      for (int mt = 0; mt < 4; ++mt) {
        short4v o;
#pragma unroll
        for (int r = 0; r < 4; ++r) o[r] = f2bf(Oacc[h][mt][r] * rl);
        *(short4v*)(Ob + ((size_t)(bb * 2048 + t)) * 1024 + hh * 64 + mt * 16 +
                    quad * 4) = o;
      }
    }
  }
#undef LOADKV
#undef WRITEKV
}

// ---------------- launcher ----------------

extern "C" void kernel_launch(void* const* d_in, const int* in_sizes, int n_in,
                              void* d_out, int out_size, void* d_ws, size_t ws_size,
                              hipStream_t stream) {
  const float* x      = (const float*)d_in[0];
  const float* w_attn = (const float*)d_in[1];
  const float* b_attn = (const float*)d_in[2];
  const float* w_proj = (const float*)d_in[3];
  const float* b_proj = (const float*)d_in[4];
  float* out = (float*)d_out;
  char* ws = (char*)d_ws;

  short* xb  = (short*)(ws);
  short* wat = (short*)(ws + 16777216);
  short* wpt = (short*)(ws + 23068672);
  short* Qb  = (short*)(ws + 25165824);
  short* Kb  = (short*)(ws + 41943040);
  short* Vtb = (short*)(ws + 58720256);
  short* Ob  = (short*)(ws + 75497472);

  prep<<<12288, 256, 0, stream>>>(x, w_attn, w_proj, xb, wat, wpt);
  gemm_qkv<<<dim3(12, 32), 512, 0, stream>>>(xb, wat, b_attn, Qb, Kb, Vtb);
  flash_attn<<<512, 256, 0, stream>>>(Qb, Kb, Vtb, Ob);
  gemm_proj<<<dim3(8, 64), 256, 0, stream>>>(Ob, wpt, b_proj, out);
}